// Round 5
// baseline (17.243 us; speedup 1.0000x reference)
//
#include <hip/hip_runtime.h>
#include <hip/hip_bf16.h>

// Masked one-hot, ONE pass, no barrier: the zero-fill store itself carries
// the 1.0f when its float4 contains a hot element.
//   - each block owns 16 KB (4096 floats) covering <=8 rows
//   - block-uniform (SGPR) precompute: hot float4 index H4[i] = (r*607+lab)>>2
//     and nibble pattern P[i] = 1<<(h&3), sentinel 0xFFFFFFFF when invalid
//   - per thread: 4 float4 stores in the exact rocclr-fill pattern
//     (lane-contiguous, 4 KB stride); data = compare chain vs the 8 sentinels
// R2 lesson: inter-lane contiguity per store instruction is mandatory.
// R3 lesson: a second dispatch costs ~7 us.
// R4 lesson: vmcnt(0)-drain barrier + dependent load tail costs ~5 us.

#define BB 256
#define NN 128
#define CC 607
#define NROWS (BB * NN)               // 32768
#define TOTAL (NROWS * CC)            // 19,890,176 floats
#define NV4   (TOTAL / 4)             // 4,972,544 float4
#define NBLOCKS (NV4 / 1024)          // 4856; block owns 4096 floats (16 KB)

__global__ __launch_bounds__(256) void onehot_onepass_kernel(const int* __restrict__ labels,
                                                             float* __restrict__ out) {
    const int b = blockIdx.x;
    const int tid = threadIdx.x;
    const int lo = b * 4096;                       // first owned float
    const unsigned rlo = (unsigned)lo / (unsigned)CC;  // one division, uniform

    // Block-uniform hot-element table (compiler keeps in SGPRs; static idx only).
    unsigned H4[8];
    int P[8];
#pragma unroll
    for (int i = 0; i < 8; ++i) {
        unsigned r = rlo + i;
        unsigned rc = (r < NROWS) ? r : (NROWS - 1);   // clamp read
        int lab = labels[rc];                          // uniform -> s_load, L2-hot
        int h = (int)(r * CC) + lab;
        bool valid = (r < NROWS) & (lab >= 0) & (h >= lo) & (h < lo + 4096);
        H4[i] = valid ? (unsigned)(h >> 2) : 0xFFFFFFFFu;  // sentinel: no match
        P[i] = 1 << (h & 3);
    }

    const unsigned F0 = (unsigned)b * 1024u + (unsigned)tid;  // thread's first float4 idx
    float4* o4 = reinterpret_cast<float4*>(out) + F0;

#pragma unroll
    for (int j = 0; j < 4; ++j) {
        const unsigned F = F0 + 256u * j;
        int pat = 0;
#pragma unroll
        for (int i = 0; i < 8; ++i)
            pat |= (F == H4[i]) ? P[i] : 0;        // v_cmp + cndmask + or
        float4 v;
        v.x = (pat & 1) ? 1.0f : 0.0f;
        v.y = (pat & 2) ? 1.0f : 0.0f;
        v.z = (pat & 4) ? 1.0f : 0.0f;
        v.w = (pat & 8) ? 1.0f : 0.0f;
        o4[j * 256] = v;                           // memset-identical pattern
    }
}

extern "C" void kernel_launch(void* const* d_in, const int* in_sizes, int n_in,
                              void* d_out, int out_size, void* d_ws, size_t ws_size,
                              hipStream_t stream) {
    // d_in[0] = obj_sem_cls_pred (unused), d_in[1] = obj_labels (int32 on device),
    // d_in[2] = cur_step, d_in[3] = total_steps (unused).
    const int* labels = (const int*)d_in[1];
    float* out = (float*)d_out;

    onehot_onepass_kernel<<<NBLOCKS, 256, 0, stream>>>(labels, out);
}